// Round 9
// baseline (210.623 us; speedup 1.0000x reference)
//
#include <hip/hip_runtime.h>

#define BD 8
#define CD 128
#define HD 96
#define WD 96
#define PD 9216      // H*W
#define ND 73728     // B*P

typedef __attribute__((ext_vector_type(8))) short short8;
typedef __attribute__((ext_vector_type(4))) float f32x4;

__device__ inline float bfu2f(unsigned int u) { return __uint_as_float(u << 16); }
__device__ inline unsigned short f2bfu(float f) {
  unsigned int u = __float_as_uint(f);
  u += 0x7fffu + ((u >> 16) & 1u);   // RNE
  return (unsigned short)(u >> 16);
}

template<bool F32>
__device__ __forceinline__ float ldv(const void* __restrict__ p, size_t i) {
  if constexpr (F32) return ((const float*)p)[i];
  else return bfu2f(((const unsigned short*)p)[i]);
}

// ---------------- storage-dtype detector: per-block partial counts (no atomics, no init) ----------------
__global__ void k_detect(const unsigned int* __restrict__ xw, int* __restrict__ dcnt) {
  __shared__ int wl[4], we[4];
  const int t = threadIdx.x;
  uint4 w = ((const uint4*)xw)[blockIdx.x * 256 + t];   // 64 blocks cover 65536 words
  int lz = (int)((w.x & 0xFFFFu) == 0u) + (int)((w.y & 0xFFFFu) == 0u) +
           (int)((w.z & 0xFFFFu) == 0u) + (int)((w.w & 0xFFFFu) == 0u);
  int e2 = (int)(((w.x >> 7) & 0xFFu) == 0xFFu) + (int)(((w.y >> 7) & 0xFFu) == 0xFFu) +
           (int)(((w.z >> 7) & 0xFFu) == 0xFFu) + (int)(((w.w >> 7) & 0xFFu) == 0xFFu);
  #pragma unroll
  for (int off = 32; off; off >>= 1) {
    lz += __shfl_down(lz, off);
    e2 += __shfl_down(e2, off);
  }
  if ((t & 63) == 0) { wl[t >> 6] = lz; we[t >> 6] = e2; }
  __syncthreads();
  if (t == 0) {
    dcnt[blockIdx.x] = wl[0] + wl[1] + wl[2] + wl[3];
    dcnt[64 + blockIdx.x] = we[0] + we[1] + we[2] + we[3];
  }
}

// ---------------- merged: flag derivation + weight/param canonicalization + dmm init ----------------
__global__ void k_cvt(const void* __restrict__ w1, const void* __restrict__ w2,
                      const void* __restrict__ gw, const void* __restrict__ gb,
                      const void* __restrict__ b1, const void* __restrict__ b2,
                      const int* __restrict__ dcnt,
                      unsigned short* __restrict__ wc, float* __restrict__ prm,
                      int* __restrict__ flag, unsigned long long* __restrict__ dmm) {
  __shared__ int sflag;
  const int t = threadIdx.x;
  if (t < 64) {
    int lz = dcnt[t], e2 = dcnt[64 + t];
    #pragma unroll
    for (int off = 32; off; off >>= 1) {
      lz += __shfl_down(lz, off);
      e2 += __shfl_down(e2, off);
    }
    if (t == 0) sflag = (lz > 4096 || e2 > 0) ? 1 : 0;   // 1 = float32 storage
  }
  __syncthreads();
  const bool f32 = sflag != 0;
  const int blk = blockIdx.x;
  if (blk < 256) {
    int i = blk * 256 + t;                   // 0..65535
    if (i < 32768)
      wc[i] = f32 ? f2bfu(((const float*)w1)[i]) : ((const unsigned short*)w1)[i];
    else {
      int u = i - 32768;
      wc[i] = f32 ? f2bfu(((const float*)w2)[u]) : ((const unsigned short*)w2)[u];
    }
  } else {
    for (int i = t; i < 640; i += 256) {
      float v;
      if (i < 128)      v = f32 ? ((const float*)gw)[i]       : bfu2f(((const unsigned short*)gw)[i]);
      else if (i < 256) v = f32 ? ((const float*)gb)[i - 128] : bfu2f(((const unsigned short*)gb)[i - 128]);
      else if (i < 512) v = f32 ? ((const float*)b1)[i - 256] : bfu2f(((const unsigned short*)b1)[i - 256]);
      else              v = f32 ? ((const float*)b2)[i - 512] : bfu2f(((const unsigned short*)b2)[i - 512]);
      prm[i] = v;
    }
    if (t < 8) dmm[t] = 0x7FEFFFFFFFFFFFFFULL;
    else if (t < 16) dmm[t - 8 + 8] = 0ULL;
    if (t == 16) *flag = sflag;
  }
}

// ---------------- stats pass: lane-per-pixel, coalesced x reads, NO xpm/LDS ----------------
// Replaces k_pmt. Per-pixel chains bit-identical to the original: s/q strictly
// c=0..127 sequential; nrm2 quarter chains c-ascending, ((q0+q1)+q2)+q3.
// GN partials: per-wave per-group sums (reassociated; GN is off the selection path).
template<bool F32>
__device__ __forceinline__ void stats_body(const void* __restrict__ x,
                                           double* __restrict__ avg, double* __restrict__ nrm,
                                           double* __restrict__ nrm2, double* __restrict__ gpart,
                                           int lb) {
  const int t = threadIdx.x;
  const int gp0 = lb * 256;
  const int b = gp0 / PD, p0 = gp0 - b * PD;
  const size_t base = (size_t)b * CD * PD + p0 + t;
  double s = 0.0, q = 0.0;
  double qq0 = 0.0, qq1 = 0.0, qq2 = 0.0, qq3 = 0.0;
  double* gslot = gpart + (size_t)(lb * 4 + (t >> 6)) * 32;
  #pragma unroll
  for (int g = 0; g < 16; ++g) {
    double gs = 0.0, gq = 0.0;
    #pragma unroll
    for (int j = 0; j < 8; ++j) {
      const int c = g * 8 + j;
      double dv = (double)ldv<F32>(x, base + (size_t)c * PD);
      s += dv;
      q += dv * dv;
      if (g < 4) qq0 += dv * dv;
      else if (g < 8) qq1 += dv * dv;
      else if (g < 12) qq2 += dv * dv;
      else qq3 += dv * dv;
      gs += dv;
      gq += dv * dv;
    }
    #pragma unroll
    for (int off = 32; off; off >>= 1) {
      gs += __shfl_down(gs, off);
      gq += __shfl_down(gq, off);
    }
    if ((t & 63) == 0) { gslot[g * 2] = gs; gslot[g * 2 + 1] = gq; }
  }
  avg[gp0 + t] = s * (1.0 / 128.0);
  nrm[gp0 + t] = sqrt(q);
  nrm2[gp0 + t] = ((qq0 + qq1) + qq2) + qq3;
}
__global__ __launch_bounds__(256) void k_stats(const void* __restrict__ x,
                                               const int* __restrict__ flag,
                                               double* __restrict__ avg,
                                               double* __restrict__ nrm,
                                               double* __restrict__ nrm2,
                                               double* __restrict__ gpart) {
  const int lb = (blockIdx.x & 7) * 36 + (blockIdx.x >> 3);   // XCD swizzle (288 = 8*36)
  if (*flag) stats_body<true>(x, avg, nrm, nrm2, gpart, lb);
  else stats_body<false>(x, avg, nrm, nrm2, gpart, lb);
}

// zero-padded Laplacian on the mean map
__device__ inline double lap_df(const double* __restrict__ a, int b, int y, int x) {
  const double* ab = a + (size_t)b * PD;
  double v = 4.0 * ab[y * WD + x];
  if (y > 0)      v -= ab[(y - 1) * WD + x];
  if (y < HD - 1) v -= ab[(y + 1) * WD + x];
  if (x > 0)      v -= ab[y * WD + x - 1];
  if (x < WD - 1) v -= ab[y * WD + x + 1];
  return fabs(v);
}

// ---------------- merged: per-batch df min/max (+dfb persist) | GN finalize ----------------
__global__ void k_mg(const double* __restrict__ avg, unsigned long long* __restrict__ dmm,
                     double* __restrict__ dfb, const double* __restrict__ gpart,
                     float* __restrict__ gn) {
  __shared__ double red[8];
  const int t = threadIdx.x;
  if (blockIdx.x < 288) {
    const int lb = ((int)blockIdx.x & 7) * 36 + ((int)blockIdx.x >> 3);  // XCD swizzle
    int gp = lb * 256 + t;                  // 256 | PD -> block never crosses batch
    int b = gp / PD, p = gp - b * PD;
    double df = lap_df(avg, b, p / WD, p % WD);
    dfb[gp] = df;                           // k_ipg phase 1b reads this
    double mn = df, mx = df;
    #pragma unroll
    for (int off = 32; off; off >>= 1) {
      mn = fmin(mn, __shfl_down(mn, off));
      mx = fmax(mx, __shfl_down(mx, off));
    }
    if ((t & 63) == 0) { red[t >> 6] = mn; red[4 + (t >> 6)] = mx; }
    __syncthreads();
    if (t == 0) {
      mn = fmin(fmin(red[0], red[1]), fmin(red[2], red[3]));
      mx = fmax(fmax(red[4], red[5]), fmax(red[6], red[7]));
      atomicMin(&dmm[b], (unsigned long long)__double_as_longlong(mn));
      atomicMax(&dmm[b + 8], (unsigned long long)__double_as_longlong(mx));
    }
  } else {
    const int bg = blockIdx.x - 288;        // b*16 + g
    const int b = bg >> 4, g = bg & 15;
    double s = 0.0, q = 0.0;
    if (t < 144) {
      const double* pp = gpart + (size_t)(b * 144 + t) * 32 + g * 2;
      s = pp[0];
      q = pp[1];
    }
    #pragma unroll
    for (int off = 32; off; off >>= 1) {
      s += __shfl_down(s, off);
      q += __shfl_down(q, off);
    }
    if ((t & 63) == 0) { red[t >> 6] = s; red[4 + (t >> 6)] = q; }
    __syncthreads();
    if (t == 0) {
      double S = ((red[0] + red[1]) + red[2]) + red[3];
      double Q = ((red[4] + red[5]) + red[6]) + red[7];
      double mu = S / 73728.0;
      double var = Q / 73728.0 - mu * mu;
      gn[bg] = (float)mu;
      gn[128 + bg] = (float)(1.0 / sqrt(var + 1e-5));
    }
  }
}

// ---------------- k_ipg: IPG + GN -> eg, 8x8 tiles; halo staged DIRECTLY from x ----------------
// xpm eliminated: staging gathers 4 channels/halo-pixel from x (lanes map to
// consecutive pixels per channel -> 40B row segments, L2-hot via XCD pinning),
// packs in-register, writes the same swizzled b128 LDS layout. Values identical
// to the old xpm path (same bfu2f conversion) -> selection bit-exact.
template<bool F32>
__device__ __forceinline__ void ipg_body(const void* __restrict__ x,
                                         const double* __restrict__ nrm,
                                         const double* __restrict__ nrm2,
                                         const double* __restrict__ dfb,
                                         const unsigned long long* __restrict__ dmm,
                                         const float* __restrict__ gn,
                                         const float* __restrict__ prm,
                                         unsigned short* __restrict__ eg,
                                         float* __restrict__ tileF,
                                         double* __restrict__ nsl, double* __restrict__ nsl2) {
  float4* tile4 = (float4*)tileF;
  const float* gwf = prm;
  const float* gbf = prm + 128;

  const int t = threadIdx.x;
  const int lb = (blockIdx.x & 7) * 144 + (blockIdx.x >> 3);  // XCD swizzle (1152 = 8*144)
  const int b = lb / 144;
  const int tid = lb - b * 144;
  const int ty = tid / 12, tx = tid - ty * 12;                // 12x12 tiles of 8x8
  const int y0 = ty * 8, x0 = tx * 8;

  // ---- stage halo from x: thread (hp = t&127, shalf = t>>7); 16 iters over quarters ----
  {
    const int hp = t & 127;
    if (hp < 100) {
      int hr = hp / 10, hc = hp - hr * 10;
      int gy = y0 - 1 + hr; gy = gy < 0 ? -gy : (gy >= HD ? 2 * HD - 2 - gy : gy);
      int gx = x0 - 1 + hc; gx = gx < 0 ? -gx : (gx >= WD ? 2 * WD - 2 - gx : gx);
      const size_t pbase = (size_t)b * CD * PD + (size_t)gy * WD + gx;
      const int sw = hp & 7;
      #pragma unroll
      for (int it = 0; it < 16; ++it) {
        int s = it * 2 + (t >> 7);          // channel-quarter 0..31
        size_t cb = pbase + (size_t)(4 * s) * PD;
        float4 v;
        v.x = ldv<F32>(x, cb);
        v.y = ldv<F32>(x, cb + PD);
        v.z = ldv<F32>(x, cb + 2 * PD);
        v.w = ldv<F32>(x, cb + 3 * PD);
        tile4[(hp * 32 + s) ^ sw] = v;
      }
      if (t < 100) nsl[t] = nrm[b * PD + gy * WD + gx];  // reflected nrm halo
    }
    if (t >= 128 && t < 192) {
      int a2 = t - 128;
      nsl2[a2] = nrm2[b * PD + (y0 + (a2 >> 3)) * WD + x0 + (a2 & 7)];
    }
  }
  __syncthreads();

  const int a = t >> 2, q = t & 3;            // pixel-in-tile, channel quarter
  const int yl = a >> 3, xl = a & 7;
  const int y = y0 + yl, xx = x0 + xl;
  const int p = y * WD + xx;
  const int cpix = (yl + 1) * 10 + (xl + 1);
  const int cub = cpix * 32 + q * 8, csw = cpix & 7;

  // ---- phase 1a: f64 dots k!=4 (uniform), cross-quarter reduced ----
  double sd[9];
  {
    float cv[32];
    #pragma unroll
    for (int j4 = 0; j4 < 8; ++j4)
      *(float4*)(cv + 4 * j4) = tile4[(cub + j4) ^ csw];
    #pragma unroll
    for (int k = 0; k < 9; ++k) {
      if (k == 4) continue;                   // center == nrm2 (chain-identical)
      int dy = k / 3, dx = k - dy * 3;
      int pix = (yl + dy) * 10 + (xl + dx);
      int ub = pix * 32 + q * 8, sw = pix & 7;
      double acc = 0.0;
      #pragma unroll
      for (int seg = 0; seg < 8; ++seg) {
        float4 nv = tile4[(ub + seg) ^ sw];
        acc += (double)cv[seg * 4 + 0] * (double)nv.x;
        acc += (double)cv[seg * 4 + 1] * (double)nv.y;
        acc += (double)cv[seg * 4 + 2] * (double)nv.z;
        acc += (double)cv[seg * 4 + 3] * (double)nv.w;
      }
      // cross-quarter sum in-wave, SAME association as original: ((q0+q1)+q2)+q3
      double v1 = __shfl_down(acc, 1);
      double v2 = __shfl_down(acc, 2);
      double v3 = __shfl_down(acc, 3);
      sd[k] = ((acc + v1) + v2) + v3;
    }
  }

  // ---- phase 1b: count, ranks, softmax weights (q==0 lanes; LDS-fed) ----
  float wv[9];
  #pragma unroll
  for (int j = 0; j < 9; ++j) wv[j] = 0.f;
  if (q == 0) {
    double dmin = __longlong_as_double((long long)dmm[b]);
    double dmax = __longlong_as_double((long long)dmm[b + 8]);
    double df = dfb[b * PD + p];
    double dn = (df - dmin) / (dmax - dmin + 1e-8);
    int kk = 1 + (int)rint(dn * 7.0);
    kk = kk < 1 ? 1 : (kk > 8 ? 8 : kk);

    sd[4] = nsl2[a];
    double np_ = fmax(nsl[cpix], 1e-12);
    #pragma unroll
    for (int k = 0; k < 9; ++k) {
      int dy = k / 3, dx = k - dy * 3;
      double nq = fmax(nsl[(yl + dy) * 10 + (xl + dx)], 1e-12);
      sd[k] = sd[k] / (np_ * nq);           // normalized sim
    }
    float w[9];
    float wsum = 0.f;
    #pragma unroll
    for (int j = 0; j < 9; ++j) {
      int rank = 0;
      #pragma unroll
      for (int i = 0; i < 9; ++i)
        rank += (sd[i] > sd[j]) || (sd[i] == sd[j] && i < j);   // stable tie rule
      w[j] = (rank < kk) ? expf((float)sd[j]) : 0.f;
      wsum += w[j];
    }
    float inv = 1.f / wsum;
    #pragma unroll
    for (int j = 0; j < 9; ++j) wv[j] = w[j] * inv;
  }
  #pragma unroll
  for (int j = 0; j < 9; ++j) wv[j] = __shfl(wv[j], (t & 63) & ~3);  // broadcast to quarters

  // ---- phase 1c: aggregate (LDS) + GroupNorm -> eg (bf16, pixel-major) ----
  {
    float og[32];
    #pragma unroll
    for (int j = 0; j < 32; ++j) og[j] = 0.f;
    #pragma unroll
    for (int k = 0; k < 9; ++k) {
      int dy = k / 3, dx = k - dy * 3;
      int pix = (yl + dy) * 10 + (xl + dx);
      int ub = pix * 32 + q * 8, sw = pix & 7;
      #pragma unroll
      for (int seg = 0; seg < 8; ++seg) {
        float4 nv = tile4[(ub + seg) ^ sw];
        og[seg * 4 + 0] += wv[k] * nv.x;
        og[seg * 4 + 1] += wv[k] * nv.y;
        og[seg * 4 + 2] += wv[k] * nv.z;
        og[seg * 4 + 3] += wv[k] * nv.w;
      }
    }
    const int g16 = b * 16;
    unsigned short* egr = eg + (size_t)(b * PD + p) * 128 + q * 32;
    #pragma unroll
    for (int seg = 0; seg < 4; ++seg) {
      float4 cA = tile4[(cub + seg * 2) ^ csw];       // center re-read (bit-identical)
      float4 cB = tile4[(cub + seg * 2 + 1) ^ csw];
      float cvv[8] = {cA.x, cA.y, cA.z, cA.w, cB.x, cB.y, cB.z, cB.w};
      int g = q * 4 + seg;
      float mu = gn[g16 + g], rs = gn[128 + g16 + g];
      unsigned int pkd[4];
      #pragma unroll
      for (int j = 0; j < 8; ++j) {
        int c = q * 32 + seg * 8 + j;
        float e = og[seg * 8 + j] + (cvv[j] - mu) * rs * gwf[c] + gbf[c];
        unsigned int h = (unsigned int)f2bfu(e);
        if (j & 1) pkd[j >> 1] |= h << 16;
        else pkd[j >> 1] = h;
      }
      uint4 v; v.x = pkd[0]; v.y = pkd[1]; v.z = pkd[2]; v.w = pkd[3];
      *(uint4*)(egr + seg * 8) = v;                   // 16B store; wave covers 4KB contiguous
    }
  }
}
__global__ __launch_bounds__(256, 3) void k_ipg(const void* __restrict__ x,
                                                const int* __restrict__ flag,
                                                const double* __restrict__ nrm,
                                                const double* __restrict__ nrm2,
                                                const double* __restrict__ dfb,
                                                const unsigned long long* __restrict__ dmm,
                                                const float* __restrict__ gn,
                                                const float* __restrict__ prm,
                                                unsigned short* __restrict__ eg) {
  __shared__ float tileF[12800];            // 51200 B halo: 10x10 px x 128 ch f32
  __shared__ double nsl[100];               // 800 B: reflected nrm halo
  __shared__ double nsl2[64];               // 512 B: nrm2 (center dots)
  if (*flag) ipg_body<true>(x, nrm, nrm2, dfb, dmm, gn, prm, eg, tileF, nsl, nsl2);
  else ipg_body<false>(x, nrm, nrm2, dfb, dmm, gn, prm, eg, tileF, nsl, nsl2);
}

// ---------------- k_ffn: eg -> FFN -> out, wave-per-N-quarter (weights in regs) ----------------
__global__ __launch_bounds__(256, 3) void k_ffn(const unsigned short* __restrict__ eg,
                                                const float* __restrict__ prm,
                                                const unsigned short* __restrict__ wc,
                                                float* __restrict__ outp) {
  __shared__ unsigned short et[64][136];    // 17408 B
  __shared__ unsigned short Hl[64][264];    // 33792 B
  const float* b1f = prm + 256;
  const float* b2f = prm + 512;

  const int t = threadIdx.x;
  const int lb = (blockIdx.x & 7) * 144 + (blockIdx.x >> 3);  // XCD swizzle: match k_ipg
  const int gp0 = lb * 64;                  // 64 | PD -> block within one batch
  const int b = gp0 / PD, p0b = gp0 - b * PD;

  const unsigned short* wc1 = wc;          // w1 [256][128]
  const unsigned short* wc2 = wc + 32768;  // w2 [128][256]
  const int lane = t & 63, wave = t >> 6;
  const int r16 = lane & 15, quad = lane >> 4;

  // ---- stage eg rows -> et LDS (16 KB contiguous, fully coalesced) ----
  {
    const uint4* eg4 = (const uint4*)(eg + (size_t)gp0 * 128);
    #pragma unroll
    for (int it = 0; it < 4; ++it) {
      int lin = it * 256 + t;               // 1024 uint4 = 64 rows x 16
      int row = lin >> 4, c8 = lin & 15;
      *(uint4*)&et[row][c8 * 8] = eg4[lin];
    }
  }
  // ---- preload wave's w1 quarter (n in [wave*64, wave*64+64)) into regs ----
  short8 wb1[16];
  #pragma unroll
  for (int kk = 0; kk < 4; ++kk)
    #pragma unroll
    for (int nt = 0; nt < 4; ++nt)
      wb1[kk * 4 + nt] = *(const short8*)(wc1 + (size_t)(wave * 64 + nt * 16 + r16) * 128 + kk * 32 + quad * 8);
  __syncthreads();

  // ---- stage 1: H[64 px][wave's 64 n] = relu(et * W1^T + b1), pure-reg MFMA ----
  f32x4 acc[16];
  #pragma unroll
  for (int i = 0; i < 16; ++i) acc[i] = (f32x4){0.f, 0.f, 0.f, 0.f};
  #pragma unroll
  for (int kk = 0; kk < 4; ++kk) {
    short8 afm[4];
    #pragma unroll
    for (int m = 0; m < 4; ++m)
      afm[m] = *(const short8*)&et[m * 16 + r16][kk * 32 + quad * 8];
    #pragma unroll
    for (int nt = 0; nt < 4; ++nt)
      #pragma unroll
      for (int m = 0; m < 4; ++m)
        acc[m * 4 + nt] = __builtin_amdgcn_mfma_f32_16x16x32_bf16(afm[m], wb1[kk * 4 + nt], acc[m * 4 + nt], 0, 0, 0);
  }
  #pragma unroll
  for (int nt = 0; nt < 4; ++nt) {
    int n = wave * 64 + nt * 16 + r16;
    float bias = b1f[n];
    #pragma unroll
    for (int m = 0; m < 4; ++m)
      #pragma unroll
      for (int r = 0; r < 4; ++r)
        Hl[m * 16 + quad * 4 + r][n] = f2bfu(fmaxf(acc[m * 4 + nt][r] + bias, 0.f));
  }
  // ---- preload wave's w2 quarter; latency hides under barrier ----
  short8 wb2[16];
  #pragma unroll
  for (int kk = 0; kk < 8; ++kk)
    #pragma unroll
    for (int nt = 0; nt < 2; ++nt)
      wb2[kk * 2 + nt] = *(const short8*)(wc2 + (size_t)(wave * 32 + nt * 16 + r16) * 256 + kk * 32 + quad * 8);
  __syncthreads();   // Hl columns are cross-wave

  // ---- stage 2: out[64 px][wave's 32 ch] = H*W2^T + b2 + et ----
  f32x4 acc2[8];
  #pragma unroll
  for (int i = 0; i < 8; ++i) acc2[i] = (f32x4){0.f, 0.f, 0.f, 0.f};
  #pragma unroll
  for (int kk = 0; kk < 8; ++kk) {
    short8 afm[4];
    #pragma unroll
    for (int m = 0; m < 4; ++m)
      afm[m] = *(const short8*)&Hl[m * 16 + r16][kk * 32 + quad * 8];
    #pragma unroll
    for (int nt = 0; nt < 2; ++nt)
      #pragma unroll
      for (int m = 0; m < 4; ++m)
        acc2[m * 2 + nt] = __builtin_amdgcn_mfma_f32_16x16x32_bf16(afm[m], wb2[kk * 2 + nt], acc2[m * 2 + nt], 0, 0, 0);
  }
  #pragma unroll
  for (int nt = 0; nt < 2; ++nt) {
    int n = wave * 32 + nt * 16 + r16;
    float bias = b2f[n];
    #pragma unroll
    for (int m = 0; m < 4; ++m) {
      int mloc0 = m * 16 + quad * 4;
      float4 o;
      o.x = acc2[m * 2 + nt][0] + bias + bfu2f(et[mloc0 + 0][n]);
      o.y = acc2[m * 2 + nt][1] + bias + bfu2f(et[mloc0 + 1][n]);
      o.z = acc2[m * 2 + nt][2] + bias + bfu2f(et[mloc0 + 2][n]);
      o.w = acc2[m * 2 + nt][3] + bias + bfu2f(et[mloc0 + 3][n]);
      *(float4*)(outp + (size_t)(b * CD + n) * PD + p0b + mloc0) = o;
    }
  }
}

extern "C" void kernel_launch(void* const* d_in, const int* in_sizes, int n_in,
                              void* d_out, int out_size, void* d_ws, size_t ws_size,
                              hipStream_t stream) {
  // dict order: x, gn_weight(128), gn_bias(128), w1(32768), b1(256), w2(32768), b2(128)
  const void* x  = d_in[0];
  const void* gw = d_in[1];
  const void* gb = d_in[2];
  const void* w1 = d_in[3];
  const void* b1 = d_in[4];
  const void* w2 = d_in[5];
  const void* b2 = d_in[6];
  float* out = (float*)d_out;

  char* ws = (char*)d_ws;
  int* flag = (int*)ws;                                      // [0,16)
  int* dcnt = (int*)(ws + 16);                               // [16,528) 128 ints
  unsigned long long* dmm = (unsigned long long*)(ws + 640); // [640,768)
  float* gn = (float*)(ws + 768);                            // [768,1792)
  float* prm = (float*)(ws + 1792);                          // [1792,4352)
  unsigned short* wc = (unsigned short*)(ws + 4352);         // 131072 -> 135424
  double* avg = (double*)(ws + 135424);                      // 589824 -> 725248
  double* nrm = (double*)(ws + 725248);                      // 589824 -> 1315072
  double* nrm2 = (double*)(ws + 1315072);                    // 589824 -> 1904896
  double* gpart = (double*)(ws + 1904896);                   // 1152*32*8 -> 2199808
  double* dfb = (double*)(ws + 2199808);                     // 589824 -> 2789632
  unsigned short* eg = (unsigned short*)(ws + 2789632);      // 18874368 -> ~21.7 MB

  k_detect<<<64, 256, 0, stream>>>((const unsigned int*)x, dcnt);
  k_cvt<<<257, 256, 0, stream>>>(w1, w2, gw, gb, b1, b2, dcnt, wc, prm, flag, dmm);
  k_stats<<<288, 256, 0, stream>>>(x, flag, avg, nrm, nrm2, gpart);
  k_mg<<<416, 256, 0, stream>>>(avg, dmm, dfb, gpart, gn);
  k_ipg<<<ND / 64, 256, 0, stream>>>(x, flag, nrm, nrm2, dfb, dmm, gn, prm, eg);
  k_ffn<<<ND / 64, 256, 0, stream>>>(eg, prm, wc, out);
}

// Round 10
// 194.177 us; speedup vs baseline: 1.0847x; 1.0847x over previous
//
#include <hip/hip_runtime.h>

#define BD 8
#define CD 128
#define HD 96
#define WD 96
#define PD 9216      // H*W
#define ND 73728     // B*P

typedef __attribute__((ext_vector_type(8))) short short8;
typedef __attribute__((ext_vector_type(4))) float f32x4;

__device__ inline float bfu2f(unsigned int u) { return __uint_as_float(u << 16); }
__device__ inline unsigned short f2bfu(float f) {
  unsigned int u = __float_as_uint(f);
  u += 0x7fffu + ((u >> 16) & 1u);   // RNE
  return (unsigned short)(u >> 16);
}

template<bool F32>
__device__ __forceinline__ float ldv(const void* __restrict__ p, size_t i) {
  if constexpr (F32) return ((const float*)p)[i];
  else return bfu2f(((const unsigned short*)p)[i]);
}

// ---------------- storage-dtype detector: per-block partial counts ----------------
__global__ void k_detect(const unsigned int* __restrict__ xw, int* __restrict__ dcnt) {
  __shared__ int wl[4], we[4];
  const int t = threadIdx.x;
  uint4 w = ((const uint4*)xw)[blockIdx.x * 256 + t];   // 64 blocks cover 65536 words
  int lz = (int)((w.x & 0xFFFFu) == 0u) + (int)((w.y & 0xFFFFu) == 0u) +
           (int)((w.z & 0xFFFFu) == 0u) + (int)((w.w & 0xFFFFu) == 0u);
  int e2 = (int)(((w.x >> 7) & 0xFFu) == 0xFFu) + (int)(((w.y >> 7) & 0xFFu) == 0xFFu) +
           (int)(((w.z >> 7) & 0xFFu) == 0xFFu) + (int)(((w.w >> 7) & 0xFFu) == 0xFFu);
  #pragma unroll
  for (int off = 32; off; off >>= 1) {
    lz += __shfl_down(lz, off);
    e2 += __shfl_down(e2, off);
  }
  if ((t & 63) == 0) { wl[t >> 6] = lz; we[t >> 6] = e2; }
  __syncthreads();
  if (t == 0) {
    dcnt[blockIdx.x] = wl[0] + wl[1] + wl[2] + wl[3];
    dcnt[64 + blockIdx.x] = we[0] + we[1] + we[2] + we[3];
  }
}

// ---------------- merged: flag derivation + weight/param canonicalization + dmm init ----------------
__global__ void k_cvt(const void* __restrict__ w1, const void* __restrict__ w2,
                      const void* __restrict__ gw, const void* __restrict__ gb,
                      const void* __restrict__ b1, const void* __restrict__ b2,
                      const int* __restrict__ dcnt,
                      unsigned short* __restrict__ wc, float* __restrict__ prm,
                      int* __restrict__ flag, unsigned long long* __restrict__ dmm) {
  __shared__ int sflag;
  const int t = threadIdx.x;
  if (t < 64) {
    int lz = dcnt[t], e2 = dcnt[64 + t];
    #pragma unroll
    for (int off = 32; off; off >>= 1) {
      lz += __shfl_down(lz, off);
      e2 += __shfl_down(e2, off);
    }
    if (t == 0) sflag = (lz > 4096 || e2 > 0) ? 1 : 0;   // 1 = float32 storage
  }
  __syncthreads();
  const bool f32 = sflag != 0;
  const int blk = blockIdx.x;
  if (blk < 256) {
    int i = blk * 256 + t;                   // 0..65535
    if (i < 32768)
      wc[i] = f32 ? f2bfu(((const float*)w1)[i]) : ((const unsigned short*)w1)[i];
    else {
      int u = i - 32768;
      wc[i] = f32 ? f2bfu(((const float*)w2)[u]) : ((const unsigned short*)w2)[u];
    }
  } else {
    for (int i = t; i < 640; i += 256) {
      float v;
      if (i < 128)      v = f32 ? ((const float*)gw)[i]       : bfu2f(((const unsigned short*)gw)[i]);
      else if (i < 256) v = f32 ? ((const float*)gb)[i - 128] : bfu2f(((const unsigned short*)gb)[i - 128]);
      else if (i < 512) v = f32 ? ((const float*)b1)[i - 256] : bfu2f(((const unsigned short*)b1)[i - 256]);
      else              v = f32 ? ((const float*)b2)[i - 512] : bfu2f(((const unsigned short*)b2)[i - 512]);
      prm[i] = v;
    }
    if (t < 8) dmm[t] = 0x7FEFFFFFFFFFFFFFULL;
    else if (t < 16) dmm[t] = 0ULL;
    if (t == 16) *flag = sflag;
  }
}

// ---------------- transpose -> pixel-major xpm (STORAGE dtype) + stats + GN partials ----------------
// xpm stored as 16-bit when input is bf16: f2bfu(bfu2f(u)) == u exactly, so the
// round-trip is the identity -> k_ipg's staged tile values are bit-identical to
// the f32-xpm path. Halves xpm HBM traffic. F32-storage path keeps f32 xpm.
// Per-pixel stats bit-exact (c=0..127 sequential chains); nrm2 quarter chains
// ((q0+q1)+q2)+q3 == k_ipg's skipped center dot.
template<bool F32>
__device__ __forceinline__ void pmt_body(const void* __restrict__ x,
                                         void* __restrict__ xpm,
                                         double* __restrict__ avg, double* __restrict__ nrm,
                                         double* __restrict__ nrm2,
                                         double* __restrict__ gpart,
                                         float (*tile)[132], int lb) {
  const int t = threadIdx.x, px = t & 63, ci = t >> 6;
  const int gp0 = lb * 64, b = gp0 / PD, p0 = gp0 - b * PD;
  double sg[4] = {0.0, 0.0, 0.0, 0.0}, qg[4] = {0.0, 0.0, 0.0, 0.0};
  for (int j = 0; j < 32; ++j) {
    int c = ci * 32 + j;
    float v = ldv<F32>(x, (size_t)(b * CD + c) * PD + p0 + px);   // coalesced
    tile[px][c] = v;
    sg[j >> 3] += (double)v;
    qg[j >> 3] += (double)v * (double)v;
  }
  #pragma unroll
  for (int g = 0; g < 4; ++g) {
    #pragma unroll
    for (int off = 32; off; off >>= 1) {
      sg[g] += __shfl_down(sg[g], off);
      qg[g] += __shfl_down(qg[g], off);
    }
  }
  if (px == 0) {
    double* gp_ = gpart + (size_t)lb * 32;
    #pragma unroll
    for (int g = 0; g < 4; ++g) {
      gp_[(ci * 4 + g) * 2 + 0] = sg[g];
      gp_[(ci * 4 + g) * 2 + 1] = qg[g];
    }
  }
  __syncthreads();
  if constexpr (F32) {
    float* xo = (float*)xpm;
    for (int i = t; i < 2048; i += 256) {
      int r = i >> 5, seg = i & 31;
      *(float4*)(xo + (size_t)(gp0 + r) * 128 + seg * 4) = *(const float4*)&tile[r][seg * 4];
    }
  } else {
    unsigned short* xo = (unsigned short*)xpm;
    for (int i = t; i < 2048; i += 256) {
      int r = i >> 5, seg = i & 31;
      ushort4 v;
      v.x = f2bfu(tile[r][seg * 4 + 0]);    // identity bits for bf16-sourced values
      v.y = f2bfu(tile[r][seg * 4 + 1]);
      v.z = f2bfu(tile[r][seg * 4 + 2]);
      v.w = f2bfu(tile[r][seg * 4 + 3]);
      *(ushort4*)(xo + (size_t)(gp0 + r) * 128 + seg * 4) = v;
    }
  }
  if (t < 64) {
    double s = 0.0, q = 0.0;
    for (int c = 0; c < 128; ++c) {
      float v = tile[t][c];
      s += (double)v;
      q += (double)v * (double)v;
    }
    double qq[4] = {0.0, 0.0, 0.0, 0.0};
    #pragma unroll
    for (int g = 0; g < 4; ++g)
      for (int i = 0; i < 32; ++i) {
        float v = tile[t][g * 32 + i];
        qq[g] += (double)v * (double)v;
      }
    avg[gp0 + t] = s * (1.0 / 128.0);
    nrm[gp0 + t] = sqrt(q);
    nrm2[gp0 + t] = ((qq[0] + qq[1]) + qq[2]) + qq[3];
  }
}
__global__ __launch_bounds__(256) void k_pmt(const void* __restrict__ x,
                                             const int* __restrict__ flag,
                                             void* __restrict__ xpm,
                                             double* __restrict__ avg,
                                             double* __restrict__ nrm,
                                             double* __restrict__ nrm2,
                                             double* __restrict__ gpart) {
  __shared__ float tile[64][132];
  const int lb = (blockIdx.x & 7) * 144 + (blockIdx.x >> 3);  // XCD swizzle (1152 = 8*144)
  if (*flag) pmt_body<true>(x, xpm, avg, nrm, nrm2, gpart, tile, lb);
  else pmt_body<false>(x, xpm, avg, nrm, nrm2, gpart, tile, lb);
}

// zero-padded Laplacian on the mean map
__device__ inline double lap_df(const double* __restrict__ a, int b, int y, int x) {
  const double* ab = a + (size_t)b * PD;
  double v = 4.0 * ab[y * WD + x];
  if (y > 0)      v -= ab[(y - 1) * WD + x];
  if (y < HD - 1) v -= ab[(y + 1) * WD + x];
  if (x > 0)      v -= ab[y * WD + x - 1];
  if (x < WD - 1) v -= ab[y * WD + x + 1];
  return fabs(v);
}

// ---------------- merged: per-batch df min/max (+dfb persist) | GN finalize ----------------
__global__ void k_mg(const double* __restrict__ avg, unsigned long long* __restrict__ dmm,
                     double* __restrict__ dfb, const double* __restrict__ gpart,
                     float* __restrict__ gn) {
  __shared__ double red[8];
  const int t = threadIdx.x;
  if (blockIdx.x < 288) {
    const int lb = ((int)blockIdx.x & 7) * 36 + ((int)blockIdx.x >> 3);  // XCD swizzle
    int gp = lb * 256 + t;                  // 256 | PD -> block never crosses batch
    int b = gp / PD, p = gp - b * PD;
    double df = lap_df(avg, b, p / WD, p % WD);
    dfb[gp] = df;                           // k_ipg phase 1b reads this
    double mn = df, mx = df;
    #pragma unroll
    for (int off = 32; off; off >>= 1) {
      mn = fmin(mn, __shfl_down(mn, off));
      mx = fmax(mx, __shfl_down(mx, off));
    }
    if ((t & 63) == 0) { red[t >> 6] = mn; red[4 + (t >> 6)] = mx; }
    __syncthreads();
    if (t == 0) {
      mn = fmin(fmin(red[0], red[1]), fmin(red[2], red[3]));
      mx = fmax(fmax(red[4], red[5]), fmax(red[6], red[7]));
      atomicMin(&dmm[b], (unsigned long long)__double_as_longlong(mn));
      atomicMax(&dmm[b + 8], (unsigned long long)__double_as_longlong(mx));
    }
  } else {
    const int bg = blockIdx.x - 288;        // b*16 + g
    const int b = bg >> 4, g = bg & 15;
    double s = 0.0, q = 0.0;
    if (t < 144) {
      const double* pp = gpart + (size_t)(b * 144 + t) * 32 + g * 2;
      s = pp[0];
      q = pp[1];
    }
    #pragma unroll
    for (int off = 32; off; off >>= 1) {
      s += __shfl_down(s, off);
      q += __shfl_down(q, off);
    }
    if ((t & 63) == 0) { red[t >> 6] = s; red[4 + (t >> 6)] = q; }
    __syncthreads();
    if (t == 0) {
      double S = ((red[0] + red[1]) + red[2]) + red[3];
      double Q = ((red[4] + red[5]) + red[6]) + red[7];
      double mu = S / 73728.0;
      double var = Q / 73728.0 - mu * mu;
      gn[bg] = (float)mu;
      gn[128 + bg] = (float)(1.0 / sqrt(var + 1e-5));
    }
  }
}

// ---------------- k_ipg: IPG + GN -> eg, 8x8 tiles + LDS halo (staged from xpm) ----------------
// r10: reverted r9's direct-x staging (scalar gathers thrashed L2: FETCH 52 MB,
// WRITE 85 MB, +13 us). xpm read in storage dtype (8B ushort4 when bf16 ->
// half the fetch); converted values bit-identical to the f32-xpm path.
template<bool F32>
__device__ __forceinline__ void ipg_body(const void* __restrict__ xpm,
                                         const double* __restrict__ nrm,
                                         const double* __restrict__ nrm2,
                                         const double* __restrict__ dfb,
                                         const unsigned long long* __restrict__ dmm,
                                         const float* __restrict__ gn,
                                         const float* __restrict__ prm,
                                         unsigned short* __restrict__ eg,
                                         float* __restrict__ tileF,
                                         double* __restrict__ nsl, double* __restrict__ nsl2) {
  float4* tile4 = (float4*)tileF;
  const float* gwf = prm;
  const float* gbf = prm + 128;

  const int t = threadIdx.x;
  const int lb = (blockIdx.x & 7) * 144 + (blockIdx.x >> 3);  // XCD swizzle (1152 = 8*144)
  const int b = lb / 144;
  const int tid = lb - b * 144;
  const int ty = tid / 12, tx = tid - ty * 12;                // 12x12 tiles of 8x8
  const int y0 = ty * 8, x0 = tx * 8;

  // ---- stage halo (XOR-swizzled) + nrm halo + nrm2 tile ----
  {
    const int s = t & 31, hpb = t >> 5;
    #pragma unroll
    for (int it = 0; it < 13; ++it) {
      int hp = it * 8 + hpb;
      if (hp < 100) {
        int hr = hp / 10, hc = hp - hr * 10;
        int gy = y0 - 1 + hr; gy = gy < 0 ? -gy : (gy >= HD ? 2 * HD - 2 - gy : gy);
        int gx = x0 - 1 + hc; gx = gx < 0 ? -gx : (gx >= WD ? 2 * WD - 2 - gx : gx);
        float4 v;
        if constexpr (F32) {
          v = *((const float4*)((const float*)xpm + (size_t)(b * PD + gy * WD + gx) * 128) + s);
        } else {
          ushort4 u = *((const ushort4*)((const unsigned short*)xpm + (size_t)(b * PD + gy * WD + gx) * 128) + s);
          v.x = bfu2f(u.x); v.y = bfu2f(u.y); v.z = bfu2f(u.z); v.w = bfu2f(u.w);
        }
        tile4[(hp * 32 + s) ^ (hp & 7)] = v;
      }
    }
    if (t < 100) {
      int hr = t / 10, hc = t - hr * 10;
      int gy = y0 - 1 + hr; gy = gy < 0 ? -gy : (gy >= HD ? 2 * HD - 2 - gy : gy);
      int gx = x0 - 1 + hc; gx = gx < 0 ? -gx : (gx >= WD ? 2 * WD - 2 - gx : gx);
      nsl[t] = nrm[b * PD + gy * WD + gx];    // reflected -> identical to neigh9 lookups
    } else if (t >= 128 && t < 192) {
      int a2 = t - 128;
      nsl2[a2] = nrm2[b * PD + (y0 + (a2 >> 3)) * WD + x0 + (a2 & 7)];
    }
  }
  __syncthreads();

  const int a = t >> 2, q = t & 3;            // pixel-in-tile, channel quarter
  const int yl = a >> 3, xl = a & 7;
  const int y = y0 + yl, xx = x0 + xl;
  const int p = y * WD + xx;
  const int cpix = (yl + 1) * 10 + (xl + 1);
  const int cub = cpix * 32 + q * 8, csw = cpix & 7;

  // ---- phase 1a: f64 dots k!=4 (uniform), cross-quarter reduced ----
  double sd[9];
  {
    float cv[32];
    #pragma unroll
    for (int j4 = 0; j4 < 8; ++j4)
      *(float4*)(cv + 4 * j4) = tile4[(cub + j4) ^ csw];
    #pragma unroll
    for (int k = 0; k < 9; ++k) {
      if (k == 4) continue;                   // center == nrm2 (chain-identical)
      int dy = k / 3, dx = k - dy * 3;
      int pix = (yl + dy) * 10 + (xl + dx);
      int ub = pix * 32 + q * 8, sw = pix & 7;
      double acc = 0.0;
      #pragma unroll
      for (int seg = 0; seg < 8; ++seg) {
        float4 nv = tile4[(ub + seg) ^ sw];
        acc += (double)cv[seg * 4 + 0] * (double)nv.x;
        acc += (double)cv[seg * 4 + 1] * (double)nv.y;
        acc += (double)cv[seg * 4 + 2] * (double)nv.z;
        acc += (double)cv[seg * 4 + 3] * (double)nv.w;
      }
      // cross-quarter sum in-wave, SAME association as original: ((q0+q1)+q2)+q3
      double v1 = __shfl_down(acc, 1);
      double v2 = __shfl_down(acc, 2);
      double v3 = __shfl_down(acc, 3);
      sd[k] = ((acc + v1) + v2) + v3;
    }
  }

  // ---- phase 1b: count, ranks, softmax weights (q==0 lanes; LDS-fed) ----
  float wv[9];
  #pragma unroll
  for (int j = 0; j < 9; ++j) wv[j] = 0.f;
  if (q == 0) {
    double dmin = __longlong_as_double((long long)dmm[b]);
    double dmax = __longlong_as_double((long long)dmm[b + 8]);
    double df = dfb[b * PD + p];
    double dn = (df - dmin) / (dmax - dmin + 1e-8);
    int kk = 1 + (int)rint(dn * 7.0);
    kk = kk < 1 ? 1 : (kk > 8 ? 8 : kk);

    sd[4] = nsl2[a];
    double np_ = fmax(nsl[cpix], 1e-12);
    #pragma unroll
    for (int k = 0; k < 9; ++k) {
      int dy = k / 3, dx = k - dy * 3;
      double nq = fmax(nsl[(yl + dy) * 10 + (xl + dx)], 1e-12);
      sd[k] = sd[k] / (np_ * nq);           // normalized sim
    }
    float w[9];
    float wsum = 0.f;
    #pragma unroll
    for (int j = 0; j < 9; ++j) {
      int rank = 0;
      #pragma unroll
      for (int i = 0; i < 9; ++i)
        rank += (sd[i] > sd[j]) || (sd[i] == sd[j] && i < j);   // stable tie rule
      w[j] = (rank < kk) ? expf((float)sd[j]) : 0.f;
      wsum += w[j];
    }
    float inv = 1.f / wsum;
    #pragma unroll
    for (int j = 0; j < 9; ++j) wv[j] = w[j] * inv;
  }
  #pragma unroll
  for (int j = 0; j < 9; ++j) wv[j] = __shfl(wv[j], (t & 63) & ~3);  // broadcast to quarters

  // ---- phase 1c: aggregate (LDS) + GroupNorm -> eg (bf16, pixel-major) ----
  {
    float og[32];
    #pragma unroll
    for (int j = 0; j < 32; ++j) og[j] = 0.f;
    #pragma unroll
    for (int k = 0; k < 9; ++k) {
      int dy = k / 3, dx = k - dy * 3;
      int pix = (yl + dy) * 10 + (xl + dx);
      int ub = pix * 32 + q * 8, sw = pix & 7;
      #pragma unroll
      for (int seg = 0; seg < 8; ++seg) {
        float4 nv = tile4[(ub + seg) ^ sw];
        og[seg * 4 + 0] += wv[k] * nv.x;
        og[seg * 4 + 1] += wv[k] * nv.y;
        og[seg * 4 + 2] += wv[k] * nv.z;
        og[seg * 4 + 3] += wv[k] * nv.w;
      }
    }
    const int g16 = b * 16;
    unsigned short* egr = eg + (size_t)(b * PD + p) * 128 + q * 32;
    #pragma unroll
    for (int seg = 0; seg < 4; ++seg) {
      float4 cA = tile4[(cub + seg * 2) ^ csw];       // center re-read (bit-identical)
      float4 cB = tile4[(cub + seg * 2 + 1) ^ csw];
      float cvv[8] = {cA.x, cA.y, cA.z, cA.w, cB.x, cB.y, cB.z, cB.w};
      int g = q * 4 + seg;
      float mu = gn[g16 + g], rs = gn[128 + g16 + g];
      unsigned int pkd[4];
      #pragma unroll
      for (int j = 0; j < 8; ++j) {
        int c = q * 32 + seg * 8 + j;
        float e = og[seg * 8 + j] + (cvv[j] - mu) * rs * gwf[c] + gbf[c];
        unsigned int h = (unsigned int)f2bfu(e);
        if (j & 1) pkd[j >> 1] |= h << 16;
        else pkd[j >> 1] = h;
      }
      uint4 v; v.x = pkd[0]; v.y = pkd[1]; v.z = pkd[2]; v.w = pkd[3];
      *(uint4*)(egr + seg * 8) = v;                   // 16B store; wave covers 4KB contiguous
    }
  }
}
__global__ __launch_bounds__(256, 3) void k_ipg(const void* __restrict__ xpm,
                                                const int* __restrict__ flag,
                                                const double* __restrict__ nrm,
                                                const double* __restrict__ nrm2,
                                                const double* __restrict__ dfb,
                                                const unsigned long long* __restrict__ dmm,
                                                const float* __restrict__ gn,
                                                const float* __restrict__ prm,
                                                unsigned short* __restrict__ eg) {
  __shared__ float tileF[12800];            // 51200 B halo: 10x10 px x 128 ch f32
  __shared__ double nsl[100];               // 800 B: reflected nrm halo
  __shared__ double nsl2[64];               // 512 B: nrm2 (center dots)
  if (*flag) ipg_body<true>(xpm, nrm, nrm2, dfb, dmm, gn, prm, eg, tileF, nsl, nsl2);
  else ipg_body<false>(xpm, nrm, nrm2, dfb, dmm, gn, prm, eg, tileF, nsl, nsl2);
}

// ---------------- k_ffn: eg -> FFN -> out, wave-per-N-quarter (weights in regs) ----------------
__global__ __launch_bounds__(256, 3) void k_ffn(const unsigned short* __restrict__ eg,
                                                const float* __restrict__ prm,
                                                const unsigned short* __restrict__ wc,
                                                float* __restrict__ outp) {
  __shared__ unsigned short et[64][136];    // 17408 B
  __shared__ unsigned short Hl[64][264];    // 33792 B
  const float* b1f = prm + 256;
  const float* b2f = prm + 512;

  const int t = threadIdx.x;
  const int lb = (blockIdx.x & 7) * 144 + (blockIdx.x >> 3);  // XCD swizzle: match k_ipg
  const int gp0 = lb * 64;                  // 64 | PD -> block within one batch
  const int b = gp0 / PD, p0b = gp0 - b * PD;

  const unsigned short* wc1 = wc;          // w1 [256][128]
  const unsigned short* wc2 = wc + 32768;  // w2 [128][256]
  const int lane = t & 63, wave = t >> 6;
  const int r16 = lane & 15, quad = lane >> 4;

  // ---- stage eg rows -> et LDS (16 KB contiguous, fully coalesced) ----
  {
    const uint4* eg4 = (const uint4*)(eg + (size_t)gp0 * 128);
    #pragma unroll
    for (int it = 0; it < 4; ++it) {
      int lin = it * 256 + t;               // 1024 uint4 = 64 rows x 16
      int row = lin >> 4, c8 = lin & 15;
      *(uint4*)&et[row][c8 * 8] = eg4[lin];
    }
  }
  // ---- preload wave's w1 quarter (n in [wave*64, wave*64+64)) into regs ----
  short8 wb1[16];
  #pragma unroll
  for (int kk = 0; kk < 4; ++kk)
    #pragma unroll
    for (int nt = 0; nt < 4; ++nt)
      wb1[kk * 4 + nt] = *(const short8*)(wc1 + (size_t)(wave * 64 + nt * 16 + r16) * 128 + kk * 32 + quad * 8);
  __syncthreads();

  // ---- stage 1: H[64 px][wave's 64 n] = relu(et * W1^T + b1), pure-reg MFMA ----
  f32x4 acc[16];
  #pragma unroll
  for (int i = 0; i < 16; ++i) acc[i] = (f32x4){0.f, 0.f, 0.f, 0.f};
  #pragma unroll
  for (int kk = 0; kk < 4; ++kk) {
    short8 afm[4];
    #pragma unroll
    for (int m = 0; m < 4; ++m)
      afm[m] = *(const short8*)&et[m * 16 + r16][kk * 32 + quad * 8];
    #pragma unroll
    for (int nt = 0; nt < 4; ++nt)
      #pragma unroll
      for (int m = 0; m < 4; ++m)
        acc[m * 4 + nt] = __builtin_amdgcn_mfma_f32_16x16x32_bf16(afm[m], wb1[kk * 4 + nt], acc[m * 4 + nt], 0, 0, 0);
  }
  #pragma unroll
  for (int nt = 0; nt < 4; ++nt) {
    int n = wave * 64 + nt * 16 + r16;
    float bias = b1f[n];
    #pragma unroll
    for (int m = 0; m < 4; ++m)
      #pragma unroll
      for (int r = 0; r < 4; ++r)
        Hl[m * 16 + quad * 4 + r][n] = f2bfu(fmaxf(acc[m * 4 + nt][r] + bias, 0.f));
  }
  // ---- preload wave's w2 quarter; latency hides under barrier ----
  short8 wb2[16];
  #pragma unroll
  for (int kk = 0; kk < 8; ++kk)
    #pragma unroll
    for (int nt = 0; nt < 2; ++nt)
      wb2[kk * 2 + nt] = *(const short8*)(wc2 + (size_t)(wave * 32 + nt * 16 + r16) * 256 + kk * 32 + quad * 8);
  __syncthreads();   // Hl columns are cross-wave

  // ---- stage 2: out[64 px][wave's 32 ch] = H*W2^T + b2 + et ----
  f32x4 acc2[8];
  #pragma unroll
  for (int i = 0; i < 8; ++i) acc2[i] = (f32x4){0.f, 0.f, 0.f, 0.f};
  #pragma unroll
  for (int kk = 0; kk < 8; ++kk) {
    short8 afm[4];
    #pragma unroll
    for (int m = 0; m < 4; ++m)
      afm[m] = *(const short8*)&Hl[m * 16 + r16][kk * 32 + quad * 8];
    #pragma unroll
    for (int nt = 0; nt < 2; ++nt)
      #pragma unroll
      for (int m = 0; m < 4; ++m)
        acc2[m * 2 + nt] = __builtin_amdgcn_mfma_f32_16x16x32_bf16(afm[m], wb2[kk * 2 + nt], acc2[m * 2 + nt], 0, 0, 0);
  }
  #pragma unroll
  for (int nt = 0; nt < 2; ++nt) {
    int n = wave * 32 + nt * 16 + r16;
    float bias = b2f[n];
    #pragma unroll
    for (int m = 0; m < 4; ++m) {
      int mloc0 = m * 16 + quad * 4;
      float4 o;
      o.x = acc2[m * 2 + nt][0] + bias + bfu2f(et[mloc0 + 0][n]);
      o.y = acc2[m * 2 + nt][1] + bias + bfu2f(et[mloc0 + 1][n]);
      o.z = acc2[m * 2 + nt][2] + bias + bfu2f(et[mloc0 + 2][n]);
      o.w = acc2[m * 2 + nt][3] + bias + bfu2f(et[mloc0 + 3][n]);
      *(float4*)(outp + (size_t)(b * CD + n) * PD + p0b + mloc0) = o;
    }
  }
}

extern "C" void kernel_launch(void* const* d_in, const int* in_sizes, int n_in,
                              void* d_out, int out_size, void* d_ws, size_t ws_size,
                              hipStream_t stream) {
  // dict order: x, gn_weight(128), gn_bias(128), w1(32768), b1(256), w2(32768), b2(128)
  const void* x  = d_in[0];
  const void* gw = d_in[1];
  const void* gb = d_in[2];
  const void* w1 = d_in[3];
  const void* b1 = d_in[4];
  const void* w2 = d_in[5];
  const void* b2 = d_in[6];
  float* out = (float*)d_out;

  char* ws = (char*)d_ws;
  int* flag = (int*)ws;                                      // [0,16)
  int* dcnt = (int*)(ws + 16);                               // [16,528) 128 ints
  unsigned long long* dmm = (unsigned long long*)(ws + 640); // [640,768)
  float* gn = (float*)(ws + 768);                            // [768,1792)
  float* prm = (float*)(ws + 1792);                          // [1792,4352)
  unsigned short* wc = (unsigned short*)(ws + 4352);         // 131072 -> 135424
  double* avg = (double*)(ws + 135424);                      // 589824 -> 725248
  double* nrm = (double*)(ws + 725248);                      // 589824 -> 1315072
  double* nrm2 = (double*)(ws + 1315072);                    // 589824 -> 1904896
  double* gpart = (double*)(ws + 1904896);                   // 294912 -> 2199808
  double* dfb = (double*)(ws + 2199808);                     // 589824 -> 2789632
  unsigned short* eg = (unsigned short*)(ws + 2789632);      // 18874368 -> 21664000
  void* xpm = (void*)(ws + 21664000);                        // <=37748736 (f32) / 18.9MB (bf16)

  k_detect<<<64, 256, 0, stream>>>((const unsigned int*)x, dcnt);
  k_cvt<<<257, 256, 0, stream>>>(w1, w2, gw, gb, b1, b2, dcnt, wc, prm, flag, dmm);
  k_pmt<<<ND / 64, 256, 0, stream>>>(x, flag, xpm, avg, nrm, nrm2, gpart);
  k_mg<<<416, 256, 0, stream>>>(avg, dmm, dfb, gpart, gn);
  k_ipg<<<ND / 64, 256, 0, stream>>>(xpm, flag, nrm, nrm2, dfb, dmm, gn, prm, eg);
  k_ffn<<<ND / 64, 256, 0, stream>>>(eg, prm, wc, out);
}

// Round 11
// 178.863 us; speedup vs baseline: 1.1776x; 1.0856x over previous
//
#include <hip/hip_runtime.h>

#define BD 8
#define CD 128
#define HD 96
#define WD 96
#define PD 9216      // H*W
#define ND 73728     // B*P

typedef __attribute__((ext_vector_type(8))) short short8;
typedef __attribute__((ext_vector_type(4))) float f32x4;

__device__ inline float bfu2f(unsigned int u) { return __uint_as_float(u << 16); }
__device__ inline unsigned short f2bfu(float f) {
  unsigned int u = __float_as_uint(f);
  u += 0x7fffu + ((u >> 16) & 1u);   // RNE
  return (unsigned short)(u >> 16);
}

template<bool F32>
__device__ __forceinline__ float ldv(const void* __restrict__ p, size_t i) {
  if constexpr (F32) return ((const float*)p)[i];
  else return bfu2f(((const unsigned short*)p)[i]);
}

// ---------------- storage-dtype detector: per-block partial counts ----------------
__global__ void k_detect(const unsigned int* __restrict__ xw, int* __restrict__ dcnt) {
  __shared__ int wl[4], we[4];
  const int t = threadIdx.x;
  uint4 w = ((const uint4*)xw)[blockIdx.x * 256 + t];   // 64 blocks cover 65536 words
  int lz = (int)((w.x & 0xFFFFu) == 0u) + (int)((w.y & 0xFFFFu) == 0u) +
           (int)((w.z & 0xFFFFu) == 0u) + (int)((w.w & 0xFFFFu) == 0u);
  int e2 = (int)(((w.x >> 7) & 0xFFu) == 0xFFu) + (int)(((w.y >> 7) & 0xFFu) == 0xFFu) +
           (int)(((w.z >> 7) & 0xFFu) == 0xFFu) + (int)(((w.w >> 7) & 0xFFu) == 0xFFu);
  #pragma unroll
  for (int off = 32; off; off >>= 1) {
    lz += __shfl_down(lz, off);
    e2 += __shfl_down(e2, off);
  }
  if ((t & 63) == 0) { wl[t >> 6] = lz; we[t >> 6] = e2; }
  __syncthreads();
  if (t == 0) {
    dcnt[blockIdx.x] = wl[0] + wl[1] + wl[2] + wl[3];
    dcnt[64 + blockIdx.x] = we[0] + we[1] + we[2] + we[3];
  }
}

// ---------------- merged: flag derivation + weight/param canonicalization + dmm init ----------------
__global__ void k_cvt(const void* __restrict__ w1, const void* __restrict__ w2,
                      const void* __restrict__ gw, const void* __restrict__ gb,
                      const void* __restrict__ b1, const void* __restrict__ b2,
                      const int* __restrict__ dcnt,
                      unsigned short* __restrict__ wc, float* __restrict__ prm,
                      int* __restrict__ flag, unsigned long long* __restrict__ dmm) {
  __shared__ int sflag;
  const int t = threadIdx.x;
  if (t < 64) {
    int lz = dcnt[t], e2 = dcnt[64 + t];
    #pragma unroll
    for (int off = 32; off; off >>= 1) {
      lz += __shfl_down(lz, off);
      e2 += __shfl_down(e2, off);
    }
    if (t == 0) sflag = (lz > 4096 || e2 > 0) ? 1 : 0;   // 1 = float32 storage
  }
  __syncthreads();
  const bool f32 = sflag != 0;
  const int blk = blockIdx.x;
  if (blk < 256) {
    int i = blk * 256 + t;                   // 0..65535
    if (i < 32768)
      wc[i] = f32 ? f2bfu(((const float*)w1)[i]) : ((const unsigned short*)w1)[i];
    else {
      int u = i - 32768;
      wc[i] = f32 ? f2bfu(((const float*)w2)[u]) : ((const unsigned short*)w2)[u];
    }
  } else {
    for (int i = t; i < 640; i += 256) {
      float v;
      if (i < 128)      v = f32 ? ((const float*)gw)[i]       : bfu2f(((const unsigned short*)gw)[i]);
      else if (i < 256) v = f32 ? ((const float*)gb)[i - 128] : bfu2f(((const unsigned short*)gb)[i - 128]);
      else if (i < 512) v = f32 ? ((const float*)b1)[i - 256] : bfu2f(((const unsigned short*)b1)[i - 256]);
      else              v = f32 ? ((const float*)b2)[i - 512] : bfu2f(((const unsigned short*)b2)[i - 512]);
      prm[i] = v;
    }
    if (t < 8) dmm[t] = 0x7FEFFFFFFFFFFFFFULL;
    else if (t < 16) dmm[t] = 0ULL;
    if (t == 16) *flag = sflag;
  }
}

// ---------------- transpose -> pixel-major f32 xpm + stats + GN partials ----------------
// r11: xpm back to f32 (A/B vs r10's bf16 xpm, which coincided with k_ipg's
// FETCH 19->49 / WRITE 18->82 MB anomaly). Staging loads vectorized: thread
// handles 8 (channel, pixel-quad) items -> 8x ushort4/float4 loads instead of
// 32 scalar bf16 loads (tile contents element-identical). Per-pixel stat chains
// unchanged (c=0..127 sequential; nrm2 quarter chains ((q0+q1)+q2)+q3).
// GN partials moved to the t<64 tail (wave shuffle; GN-path only, reassoc OK).
template<bool F32>
__device__ __forceinline__ void pmt_body(const void* __restrict__ x,
                                         float* __restrict__ xpm,
                                         double* __restrict__ avg, double* __restrict__ nrm,
                                         double* __restrict__ nrm2,
                                         double* __restrict__ gpart,
                                         float (*tile)[132], int lb) {
  const int t = threadIdx.x;
  const int gp0 = lb * 64, b = gp0 / PD, p0 = gp0 - b * PD;
  #pragma unroll
  for (int i = 0; i < 8; ++i) {
    int item = i * 256 + t;                 // 2048 = 128 c x 16 pixel-quads
    int c = item >> 4, pq = item & 15;
    const size_t src = (size_t)(b * CD + c) * PD + p0 + pq * 4;
    if constexpr (F32) {
      float4 v = *(const float4*)((const float*)x + src);
      tile[pq * 4 + 0][c] = v.x; tile[pq * 4 + 1][c] = v.y;
      tile[pq * 4 + 2][c] = v.z; tile[pq * 4 + 3][c] = v.w;
    } else {
      ushort4 u = *(const ushort4*)((const unsigned short*)x + src);
      tile[pq * 4 + 0][c] = bfu2f(u.x); tile[pq * 4 + 1][c] = bfu2f(u.y);
      tile[pq * 4 + 2][c] = bfu2f(u.z); tile[pq * 4 + 3][c] = bfu2f(u.w);
    }
  }
  __syncthreads();
  for (int i = t; i < 2048; i += 256) {
    int r = i >> 5, seg = i & 31;
    *(float4*)(xpm + (size_t)(gp0 + r) * 128 + seg * 4) = *(const float4*)&tile[r][seg * 4];
  }
  if (t < 64) {
    double s = 0.0, q = 0.0;
    for (int c = 0; c < 128; ++c) {
      float v = tile[t][c];
      s += (double)v;
      q += (double)v * (double)v;
    }
    double qq[4] = {0.0, 0.0, 0.0, 0.0};
    #pragma unroll
    for (int g = 0; g < 4; ++g)
      for (int i2 = 0; i2 < 32; ++i2) {
        float v = tile[t][g * 32 + i2];
        qq[g] += (double)v * (double)v;
      }
    avg[gp0 + t] = s * (1.0 / 128.0);
    nrm[gp0 + t] = sqrt(q);
    nrm2[gp0 + t] = ((qq[0] + qq[1]) + qq[2]) + qq[3];
    // GN partials: 16 groups x 8 ch, reduced over this wave's 64 pixels
    double* gp_ = gpart + (size_t)lb * 32;
    for (int g = 0; g < 16; ++g) {
      double gs = 0.0, gq = 0.0;
      #pragma unroll
      for (int j = 0; j < 8; ++j) {
        double dv = (double)tile[t][g * 8 + j];
        gs += dv;
        gq += dv * dv;
      }
      #pragma unroll
      for (int off = 32; off; off >>= 1) {
        gs += __shfl_down(gs, off);
        gq += __shfl_down(gq, off);
      }
      if (t == 0) { gp_[g * 2] = gs; gp_[g * 2 + 1] = gq; }
    }
  }
}
__global__ __launch_bounds__(256) void k_pmt(const void* __restrict__ x,
                                             const int* __restrict__ flag,
                                             float* __restrict__ xpm,
                                             double* __restrict__ avg,
                                             double* __restrict__ nrm,
                                             double* __restrict__ nrm2,
                                             double* __restrict__ gpart) {
  __shared__ float tile[64][132];
  const int lb = (blockIdx.x & 7) * 144 + (blockIdx.x >> 3);  // XCD swizzle (1152 = 8*144)
  if (*flag) pmt_body<true>(x, xpm, avg, nrm, nrm2, gpart, tile, lb);
  else pmt_body<false>(x, xpm, avg, nrm, nrm2, gpart, tile, lb);
}

// zero-padded Laplacian on the mean map
__device__ inline double lap_df(const double* __restrict__ a, int b, int y, int x) {
  const double* ab = a + (size_t)b * PD;
  double v = 4.0 * ab[y * WD + x];
  if (y > 0)      v -= ab[(y - 1) * WD + x];
  if (y < HD - 1) v -= ab[(y + 1) * WD + x];
  if (x > 0)      v -= ab[y * WD + x - 1];
  if (x < WD - 1) v -= ab[y * WD + x + 1];
  return fabs(v);
}

// ---------------- merged: per-batch df min/max (+dfb persist) | GN finalize ----------------
__global__ void k_mg(const double* __restrict__ avg, unsigned long long* __restrict__ dmm,
                     double* __restrict__ dfb, const double* __restrict__ gpart,
                     float* __restrict__ gn) {
  __shared__ double red[8];
  const int t = threadIdx.x;
  if (blockIdx.x < 288) {
    const int lb = ((int)blockIdx.x & 7) * 36 + ((int)blockIdx.x >> 3);  // XCD swizzle
    int gp = lb * 256 + t;                  // 256 | PD -> block never crosses batch
    int b = gp / PD, p = gp - b * PD;
    double df = lap_df(avg, b, p / WD, p % WD);
    dfb[gp] = df;                           // k_ipg phase 1b reads this
    double mn = df, mx = df;
    #pragma unroll
    for (int off = 32; off; off >>= 1) {
      mn = fmin(mn, __shfl_down(mn, off));
      mx = fmax(mx, __shfl_down(mx, off));
    }
    if ((t & 63) == 0) { red[t >> 6] = mn; red[4 + (t >> 6)] = mx; }
    __syncthreads();
    if (t == 0) {
      mn = fmin(fmin(red[0], red[1]), fmin(red[2], red[3]));
      mx = fmax(fmax(red[4], red[5]), fmax(red[6], red[7]));
      atomicMin(&dmm[b], (unsigned long long)__double_as_longlong(mn));
      atomicMax(&dmm[b + 8], (unsigned long long)__double_as_longlong(mx));
    }
  } else {
    const int bg = blockIdx.x - 288;        // b*16 + g
    const int b = bg >> 4, g = bg & 15;
    double s = 0.0, q = 0.0;
    if (t < 144) {
      const double* pp = gpart + (size_t)(b * 144 + t) * 32 + g * 2;
      s = pp[0];
      q = pp[1];
    }
    #pragma unroll
    for (int off = 32; off; off >>= 1) {
      s += __shfl_down(s, off);
      q += __shfl_down(q, off);
    }
    if ((t & 63) == 0) { red[t >> 6] = s; red[4 + (t >> 6)] = q; }
    __syncthreads();
    if (t == 0) {
      double S = ((red[0] + red[1]) + red[2]) + red[3];
      double Q = ((red[4] + red[5]) + red[6]) + red[7];
      double mu = S / 73728.0;
      double var = Q / 73728.0 - mu * mu;
      gn[bg] = (float)mu;
      gn[128 + bg] = (float)(1.0 / sqrt(var + 1e-5));
    }
  }
}

// ---------------- k_ipg: IPG + GN -> eg, 8x8 tiles + LDS halo (f32 xpm, r8 path) ----------------
__global__ __launch_bounds__(256, 3) void k_ipg(const float* __restrict__ xpm,
                                                const double* __restrict__ nrm,
                                                const double* __restrict__ nrm2,
                                                const double* __restrict__ dfb,
                                                const unsigned long long* __restrict__ dmm,
                                                const float* __restrict__ gn,
                                                const float* __restrict__ prm,
                                                unsigned short* __restrict__ eg) {
  __shared__ float tileF[12800];            // 51200 B halo: 10x10 px x 128 ch f32
  __shared__ double nsl[100];               // 800 B: reflected nrm halo
  __shared__ double nsl2[64];               // 512 B: nrm2 (center dots)
  float4* tile4 = (float4*)tileF;
  const float* gwf = prm;
  const float* gbf = prm + 128;

  const int t = threadIdx.x;
  const int lb = (blockIdx.x & 7) * 144 + (blockIdx.x >> 3);  // XCD swizzle (1152 = 8*144)
  const int b = lb / 144;
  const int tid = lb - b * 144;
  const int ty = tid / 12, tx = tid - ty * 12;                // 12x12 tiles of 8x8
  const int y0 = ty * 8, x0 = tx * 8;

  // ---- stage halo (XOR-swizzled) + nrm halo + nrm2 tile ----
  {
    const int s = t & 31, hpb = t >> 5;
    #pragma unroll
    for (int it = 0; it < 13; ++it) {
      int hp = it * 8 + hpb;
      if (hp < 100) {
        int hr = hp / 10, hc = hp - hr * 10;
        int gy = y0 - 1 + hr; gy = gy < 0 ? -gy : (gy >= HD ? 2 * HD - 2 - gy : gy);
        int gx = x0 - 1 + hc; gx = gx < 0 ? -gx : (gx >= WD ? 2 * WD - 2 - gx : gx);
        const float4* src = (const float4*)(xpm + (size_t)(b * PD + gy * WD + gx) * 128) + s;
        tile4[(hp * 32 + s) ^ (hp & 7)] = *src;
      }
    }
    if (t < 100) {
      int hr = t / 10, hc = t - hr * 10;
      int gy = y0 - 1 + hr; gy = gy < 0 ? -gy : (gy >= HD ? 2 * HD - 2 - gy : gy);
      int gx = x0 - 1 + hc; gx = gx < 0 ? -gx : (gx >= WD ? 2 * WD - 2 - gx : gx);
      nsl[t] = nrm[b * PD + gy * WD + gx];    // reflected -> identical to neigh9 lookups
    } else if (t >= 128 && t < 192) {
      int a2 = t - 128;
      nsl2[a2] = nrm2[b * PD + (y0 + (a2 >> 3)) * WD + x0 + (a2 & 7)];
    }
  }
  __syncthreads();

  const int a = t >> 2, q = t & 3;            // pixel-in-tile, channel quarter
  const int yl = a >> 3, xl = a & 7;
  const int y = y0 + yl, xx = x0 + xl;
  const int p = y * WD + xx;
  const int cpix = (yl + 1) * 10 + (xl + 1);
  const int cub = cpix * 32 + q * 8, csw = cpix & 7;

  // ---- phase 1a: f64 dots k!=4 (uniform), cross-quarter reduced ----
  double sd[9];
  {
    float cv[32];
    #pragma unroll
    for (int j4 = 0; j4 < 8; ++j4)
      *(float4*)(cv + 4 * j4) = tile4[(cub + j4) ^ csw];
    #pragma unroll
    for (int k = 0; k < 9; ++k) {
      if (k == 4) continue;                   // center == nrm2 (chain-identical)
      int dy = k / 3, dx = k - dy * 3;
      int pix = (yl + dy) * 10 + (xl + dx);
      int ub = pix * 32 + q * 8, sw = pix & 7;
      double acc = 0.0;
      #pragma unroll
      for (int seg = 0; seg < 8; ++seg) {
        float4 nv = tile4[(ub + seg) ^ sw];
        acc += (double)cv[seg * 4 + 0] * (double)nv.x;
        acc += (double)cv[seg * 4 + 1] * (double)nv.y;
        acc += (double)cv[seg * 4 + 2] * (double)nv.z;
        acc += (double)cv[seg * 4 + 3] * (double)nv.w;
      }
      // cross-quarter sum in-wave, SAME association as original: ((q0+q1)+q2)+q3
      double v1 = __shfl_down(acc, 1);
      double v2 = __shfl_down(acc, 2);
      double v3 = __shfl_down(acc, 3);
      sd[k] = ((acc + v1) + v2) + v3;
    }
  }

  // ---- phase 1b: count, ranks, softmax weights (q==0 lanes; LDS-fed) ----
  float wv[9];
  #pragma unroll
  for (int j = 0; j < 9; ++j) wv[j] = 0.f;
  if (q == 0) {
    double dmin = __longlong_as_double((long long)dmm[b]);
    double dmax = __longlong_as_double((long long)dmm[b + 8]);
    double df = dfb[b * PD + p];
    double dn = (df - dmin) / (dmax - dmin + 1e-8);
    int kk = 1 + (int)rint(dn * 7.0);
    kk = kk < 1 ? 1 : (kk > 8 ? 8 : kk);

    sd[4] = nsl2[a];
    double np_ = fmax(nsl[cpix], 1e-12);
    #pragma unroll
    for (int k = 0; k < 9; ++k) {
      int dy = k / 3, dx = k - dy * 3;
      double nq = fmax(nsl[(yl + dy) * 10 + (xl + dx)], 1e-12);
      sd[k] = sd[k] / (np_ * nq);           // normalized sim
    }
    float w[9];
    float wsum = 0.f;
    #pragma unroll
    for (int j = 0; j < 9; ++j) {
      int rank = 0;
      #pragma unroll
      for (int i = 0; i < 9; ++i)
        rank += (sd[i] > sd[j]) || (sd[i] == sd[j] && i < j);   // stable tie rule
      w[j] = (rank < kk) ? expf((float)sd[j]) : 0.f;
      wsum += w[j];
    }
    float inv = 1.f / wsum;
    #pragma unroll
    for (int j = 0; j < 9; ++j) wv[j] = w[j] * inv;
  }
  #pragma unroll
  for (int j = 0; j < 9; ++j) wv[j] = __shfl(wv[j], (t & 63) & ~3);  // broadcast to quarters

  // ---- phase 1c: aggregate (LDS) + GroupNorm -> eg (bf16, pixel-major) ----
  {
    float og[32];
    #pragma unroll
    for (int j = 0; j < 32; ++j) og[j] = 0.f;
    #pragma unroll
    for (int k = 0; k < 9; ++k) {
      int dy = k / 3, dx = k - dy * 3;
      int pix = (yl + dy) * 10 + (xl + dx);
      int ub = pix * 32 + q * 8, sw = pix & 7;
      #pragma unroll
      for (int seg = 0; seg < 8; ++seg) {
        float4 nv = tile4[(ub + seg) ^ sw];
        og[seg * 4 + 0] += wv[k] * nv.x;
        og[seg * 4 + 1] += wv[k] * nv.y;
        og[seg * 4 + 2] += wv[k] * nv.z;
        og[seg * 4 + 3] += wv[k] * nv.w;
      }
    }
    const int g16 = b * 16;
    unsigned short* egr = eg + (size_t)(b * PD + p) * 128 + q * 32;
    #pragma unroll
    for (int seg = 0; seg < 4; ++seg) {
      float4 cA = tile4[(cub + seg * 2) ^ csw];       // center re-read (bit-identical)
      float4 cB = tile4[(cub + seg * 2 + 1) ^ csw];
      float cvv[8] = {cA.x, cA.y, cA.z, cA.w, cB.x, cB.y, cB.z, cB.w};
      int g = q * 4 + seg;
      float mu = gn[g16 + g], rs = gn[128 + g16 + g];
      unsigned int pkd[4];
      #pragma unroll
      for (int j = 0; j < 8; ++j) {
        int c = q * 32 + seg * 8 + j;
        float e = og[seg * 8 + j] + (cvv[j] - mu) * rs * gwf[c] + gbf[c];
        unsigned int h = (unsigned int)f2bfu(e);
        if (j & 1) pkd[j >> 1] |= h << 16;
        else pkd[j >> 1] = h;
      }
      uint4 v; v.x = pkd[0]; v.y = pkd[1]; v.z = pkd[2]; v.w = pkd[3];
      *(uint4*)(egr + seg * 8) = v;                   // 16B store; wave covers 4KB contiguous
    }
  }
}

// ---------------- k_ffn: eg -> FFN -> out, wave-per-N-quarter (weights in regs) ----------------
__global__ __launch_bounds__(256, 3) void k_ffn(const unsigned short* __restrict__ eg,
                                                const float* __restrict__ prm,
                                                const unsigned short* __restrict__ wc,
                                                float* __restrict__ outp) {
  __shared__ unsigned short et[64][136];    // 17408 B
  __shared__ unsigned short Hl[64][264];    // 33792 B
  const float* b1f = prm + 256;
  const float* b2f = prm + 512;

  const int t = threadIdx.x;
  const int lb = (blockIdx.x & 7) * 144 + (blockIdx.x >> 3);  // XCD swizzle: match k_ipg
  const int gp0 = lb * 64;                  // 64 | PD -> block within one batch
  const int b = gp0 / PD, p0b = gp0 - b * PD;

  const unsigned short* wc1 = wc;          // w1 [256][128]
  const unsigned short* wc2 = wc + 32768;  // w2 [128][256]
  const int lane = t & 63, wave = t >> 6;
  const int r16 = lane & 15, quad = lane >> 4;

  // ---- stage eg rows -> et LDS (16 KB contiguous, fully coalesced) ----
  {
    const uint4* eg4 = (const uint4*)(eg + (size_t)gp0 * 128);
    #pragma unroll
    for (int it = 0; it < 4; ++it) {
      int lin = it * 256 + t;               // 1024 uint4 = 64 rows x 16
      int row = lin >> 4, c8 = lin & 15;
      *(uint4*)&et[row][c8 * 8] = eg4[lin];
    }
  }
  // ---- preload wave's w1 quarter (n in [wave*64, wave*64+64)) into regs ----
  short8 wb1[16];
  #pragma unroll
  for (int kk = 0; kk < 4; ++kk)
    #pragma unroll
    for (int nt = 0; nt < 4; ++nt)
      wb1[kk * 4 + nt] = *(const short8*)(wc1 + (size_t)(wave * 64 + nt * 16 + r16) * 128 + kk * 32 + quad * 8);
  __syncthreads();

  // ---- stage 1: H[64 px][wave's 64 n] = relu(et * W1^T + b1), pure-reg MFMA ----
  f32x4 acc[16];
  #pragma unroll
  for (int i = 0; i < 16; ++i) acc[i] = (f32x4){0.f, 0.f, 0.f, 0.f};
  #pragma unroll
  for (int kk = 0; kk < 4; ++kk) {
    short8 afm[4];
    #pragma unroll
    for (int m = 0; m < 4; ++m)
      afm[m] = *(const short8*)&et[m * 16 + r16][kk * 32 + quad * 8];
    #pragma unroll
    for (int nt = 0; nt < 4; ++nt)
      #pragma unroll
      for (int m = 0; m < 4; ++m)
        acc[m * 4 + nt] = __builtin_amdgcn_mfma_f32_16x16x32_bf16(afm[m], wb1[kk * 4 + nt], acc[m * 4 + nt], 0, 0, 0);
  }
  #pragma unroll
  for (int nt = 0; nt < 4; ++nt) {
    int n = wave * 64 + nt * 16 + r16;
    float bias = b1f[n];
    #pragma unroll
    for (int m = 0; m < 4; ++m)
      #pragma unroll
      for (int r = 0; r < 4; ++r)
        Hl[m * 16 + quad * 4 + r][n] = f2bfu(fmaxf(acc[m * 4 + nt][r] + bias, 0.f));
  }
  // ---- preload wave's w2 quarter; latency hides under barrier ----
  short8 wb2[16];
  #pragma unroll
  for (int kk = 0; kk < 8; ++kk)
    #pragma unroll
    for (int nt = 0; nt < 2; ++nt)
      wb2[kk * 2 + nt] = *(const short8*)(wc2 + (size_t)(wave * 32 + nt * 16 + r16) * 256 + kk * 32 + quad * 8);
  __syncthreads();   // Hl columns are cross-wave

  // ---- stage 2: out[64 px][wave's 32 ch] = H*W2^T + b2 + et ----
  f32x4 acc2[8];
  #pragma unroll
  for (int i = 0; i < 8; ++i) acc2[i] = (f32x4){0.f, 0.f, 0.f, 0.f};
  #pragma unroll
  for (int kk = 0; kk < 8; ++kk) {
    short8 afm[4];
    #pragma unroll
    for (int m = 0; m < 4; ++m)
      afm[m] = *(const short8*)&Hl[m * 16 + r16][kk * 32 + quad * 8];
    #pragma unroll
    for (int nt = 0; nt < 2; ++nt)
      #pragma unroll
      for (int m = 0; m < 4; ++m)
        acc2[m * 2 + nt] = __builtin_amdgcn_mfma_f32_16x16x32_bf16(afm[m], wb2[kk * 2 + nt], acc2[m * 2 + nt], 0, 0, 0);
  }
  #pragma unroll
  for (int nt = 0; nt < 2; ++nt) {
    int n = wave * 32 + nt * 16 + r16;
    float bias = b2f[n];
    #pragma unroll
    for (int m = 0; m < 4; ++m) {
      int mloc0 = m * 16 + quad * 4;
      float4 o;
      o.x = acc2[m * 2 + nt][0] + bias + bfu2f(et[mloc0 + 0][n]);
      o.y = acc2[m * 2 + nt][1] + bias + bfu2f(et[mloc0 + 1][n]);
      o.z = acc2[m * 2 + nt][2] + bias + bfu2f(et[mloc0 + 2][n]);
      o.w = acc2[m * 2 + nt][3] + bias + bfu2f(et[mloc0 + 3][n]);
      *(float4*)(outp + (size_t)(b * CD + n) * PD + p0b + mloc0) = o;
    }
  }
}

extern "C" void kernel_launch(void* const* d_in, const int* in_sizes, int n_in,
                              void* d_out, int out_size, void* d_ws, size_t ws_size,
                              hipStream_t stream) {
  // dict order: x, gn_weight(128), gn_bias(128), w1(32768), b1(256), w2(32768), b2(128)
  const void* x  = d_in[0];
  const void* gw = d_in[1];
  const void* gb = d_in[2];
  const void* w1 = d_in[3];
  const void* b1 = d_in[4];
  const void* w2 = d_in[5];
  const void* b2 = d_in[6];
  float* out = (float*)d_out;

  char* ws = (char*)d_ws;
  int* flag = (int*)ws;                                      // [0,16)
  int* dcnt = (int*)(ws + 16);                               // [16,528) 128 ints
  unsigned long long* dmm = (unsigned long long*)(ws + 640); // [640,768)
  float* gn = (float*)(ws + 768);                            // [768,1792)
  float* prm = (float*)(ws + 1792);                          // [1792,4352)
  unsigned short* wc = (unsigned short*)(ws + 4352);         // 131072 -> 135424
  double* avg = (double*)(ws + 135424);                      // 589824 -> 725248
  double* nrm = (double*)(ws + 725248);                      // 589824 -> 1315072
  double* nrm2 = (double*)(ws + 1315072);                    // 589824 -> 1904896
  double* gpart = (double*)(ws + 1904896);                   // 294912 -> 2199808
  double* dfb = (double*)(ws + 2199808);                     // 589824 -> 2789632
  unsigned short* eg = (unsigned short*)(ws + 2789632);      // 18874368 -> 21664000
  float* xpm = (float*)(ws + 21664000);                      // 37748736 -> ~59.4 MB

  k_detect<<<64, 256, 0, stream>>>((const unsigned int*)x, dcnt);
  k_cvt<<<257, 256, 0, stream>>>(w1, w2, gw, gb, b1, b2, dcnt, wc, prm, flag, dmm);
  k_pmt<<<ND / 64, 256, 0, stream>>>(x, flag, xpm, avg, nrm, nrm2, gpart);
  k_mg<<<416, 256, 0, stream>>>(avg, dmm, dfb, gpart, gn);
  k_ipg<<<ND / 64, 256, 0, stream>>>(xpm, nrm, nrm2, dfb, dmm, gn, prm, eg);
  k_ffn<<<ND / 64, 256, 0, stream>>>(eg, prm, wc, out);
}